// Round 8
// baseline (314.457 us; speedup 1.0000x reference)
//
#include <hip/hip_runtime.h>
#include <math.h>

#define BB 2
#define TT 2048
#define DD 1024
#define NTHREADS 256

#define RT 64               // rows per score tile
#define CT 128              // cols per score tile (= top-K window width)
#define DC 32               // d-halves per chunk = 1 MFMA K-step
#define NCHUNK (DD / DC)    // 32
#define NJC (TT / CT)       // 16 windows per row
#define KMAX 16
#define CST 132             // score-tile stride: 4 mod 32 -> 2-way (free) scans
#define NTILES 272          // causal 64x128 tiles per batch
#define NROWS (BB * TT)     // 4096 global rows
#define CSLAB ((uint32_t)(NROWS * DC))     // halves per chunk slab (256 KB)
#define PLANE ((uint32_t)(BB * TT * DD))   // halves per plane (hi->lo offset)
#define HBUF 12288          // halves per staging buffer (24 KB)

// K-blocked plane layout: half (row, d) lives at plane[(d/32)*NROWS*32 + row*32 + d%32].
// A chunk c of any 16-row band is 1 KB contiguous -> every global_load_lds is a
// full-line, sequential read.

typedef _Float16 half8  __attribute__((ext_vector_type(8)));
typedef _Float16 half4v __attribute__((ext_vector_type(4)));
typedef float    float4v __attribute__((ext_vector_type(4)));

#define GLD16(gp, lp) __builtin_amdgcn_global_load_lds(                         \
    (const __attribute__((address_space(1))) unsigned int*)(gp),                \
    (__attribute__((address_space(3))) unsigned int*)(lp), 16, 0, 0)

__device__ __forceinline__ float gelu_exact(float t) {
    return 0.5f * t * (1.0f + erff(t * 0.70710678118654752f));
}

// ---- Kernel P: split fp32 h into fp16 hi/lo planes, K-blocked layout ----
__global__ __launch_bounds__(NTHREADS) void split_kernel(
    const float* __restrict__ h,
    _Float16* __restrict__ hiP,
    _Float16* __restrict__ loP)
{
    const int idx = blockIdx.x * NTHREADS + threadIdx.x;   // float4 index
    const float4 v = ((const float4*)h)[idx];
    const float xs[4] = {v.x, v.y, v.z, v.w};
    half4v hi, lo;
    #pragma unroll
    for (int u = 0; u < 4; ++u) {
        const _Float16 hh = (_Float16)xs[u];
        hi[u] = hh;
        lo[u] = (_Float16)(xs[u] - (float)hh);
    }
    const uint32_t tot  = (uint32_t)idx * 4u;      // half index in row-major h
    const uint32_t grow = tot >> 10;               // global row (DD=1024)
    const uint32_t wh   = tot & 1023u;             // half within row
    const uint32_t off  = ((wh >> 5) * (uint32_t)NROWS + grow) * 32u + (wh & 31u);
    *(half4v*)(hiP + off) = hi;
    *(half4v*)(loP + off) = lo;
}

// ---- Kernel S: causal 64x128 score tile, DMA-staged split-fp16 MFMA,
//      depth-2 counted-vmcnt pipeline; K-blocked global layout makes every
//      global_load_lds a contiguous full-line read. (r5 anchor structure) ----
// Staging buffer layout (granule = 16 B = 8 halves, fragment-lane order):
//   A-hi granules [0,256), A-lo [256,512), B-hi [512,1024), B-lo [1024,1536).
//   granule n (within region): row = 16*band + (n&15), k-oct = (n>>4)&3,
//   band = n>>6. Global addr of granule = pl*PLANE + c*CSLAB + grow*DC + oct*8.
__global__ __launch_bounds__(NTHREADS) void score_topk_kernel(
    const _Float16* __restrict__ hiP,   // loP = hiP + PLANE
    float* __restrict__ pval,   // (B,T,NJC,KMAX)
    int*   __restrict__ pidx,   // (B,T,NJC,KMAX)
    int K)
{
    __shared__ __align__(16) char smem_raw[49152];  // 2x24KB staging / 64x132 f32 scores
    _Float16* sm  = (_Float16*)smem_raw;
    float* scores = (float*)smem_raw;

    // triangular decode: p -> (it, jc); it in [0,32), jc in [0, it/2]
    const int b = blockIdx.y;
    const int p = blockIdx.x;
    int g = (int)(0.5f * (sqrtf(4.0f * (float)p + 1.0f) - 1.0f));
    while ((g + 1) * (g + 2) <= p) ++g;
    while (g * (g + 1) > p) --g;
    const int qq = p - g * (g + 1);
    const int it = 2 * g + qq / (g + 1);
    const int jc = qq % (g + 1);
    const int i0 = it * RT, j0 = jc * CT;

    const int tid  = threadIdx.x;
    const int lane = tid & 63, wave = tid >> 6;
    const int wr = wave & 1, wc = wave >> 1;

    // 6 DMA slots/thread/chunk: granule gr = tid + 256*slot
    uint32_t goff[6];
    #pragma unroll
    for (int slot = 0; slot < 6; ++slot) {
        const int gr = tid + NTHREADS * slot;   // 0..1535
        int n, row; uint32_t pl;
        if (gr < 256)       { n = gr;        pl = 0; row = i0 + 16 * (n >> 6) + (n & 15); }
        else if (gr < 512)  { n = gr - 256;  pl = 1; row = i0 + 16 * (n >> 6) + (n & 15); }
        else if (gr < 1024) { n = gr - 512;  pl = 0; row = j0 + 16 * (n >> 6) + (n & 15); }
        else                { n = gr - 1024; pl = 1; row = j0 + 16 * (n >> 6) + (n & 15); }
        const int oct = (n >> 4) & 3;
        goff[slot] = pl * PLANE + (uint32_t)(b * TT + row) * DC + (uint32_t)oct * 8;
    }

    float4v acc[2][4];
    #pragma unroll
    for (int rb = 0; rb < 2; ++rb)
        #pragma unroll
        for (int cb = 0; cb < 4; ++cb)
            acc[rb][cb] = (float4v){0.f, 0.f, 0.f, 0.f};

    // prologue: DMA chunk 0 -> buf0 AND chunk 1 -> buf1; no drain, no barrier.
    #pragma unroll
    for (int t = 0; t < 6; ++t)
        GLD16(hiP + goff[t], &sm[(size_t)(tid + NTHREADS * t) * 8]);
    #pragma unroll
    for (int t = 0; t < 6; ++t)
        GLD16(hiP + goff[t] + CSLAB, &sm[HBUF + (size_t)(tid + NTHREADS * t) * 8]);

    for (int c = 0; c < NCHUNK; ++c) {
        const int cur = (c & 1) ? HBUF : 0;

        // wait for chunk c only; chunk c+1 stays in flight across the barrier
        if (c < NCHUNK - 1) asm volatile("s_waitcnt vmcnt(6)" ::: "memory");
        else                asm volatile("s_waitcnt vmcnt(0)" ::: "memory");
        __builtin_amdgcn_s_barrier();          // chunk c visible to all waves
        asm volatile("" ::: "memory");

        // fragments from cur
        half8 ah[2], al[2], bh[4], bl[4];
        #pragma unroll
        for (int rb = 0; rb < 2; ++rb) {
            const int band = 2 * wr + rb;
            ah[rb] = *(const half8*)&sm[cur +        (band * 64 + lane) * 8];
            al[rb] = *(const half8*)&sm[cur + 2048 + (band * 64 + lane) * 8];
        }
        #pragma unroll
        for (int cb = 0; cb < 4; ++cb) {
            const int band = 4 * wc + cb;
            bh[cb] = *(const half8*)&sm[cur + 4096 + (band * 64 + lane) * 8];
            bl[cb] = *(const half8*)&sm[cur + 8192 + (band * 64 + lane) * 8];
        }

        // all reads of buf[cur] complete in every wave -> safe to overwrite
        asm volatile("s_waitcnt lgkmcnt(0)" ::: "memory");
        __builtin_amdgcn_s_barrier();
        asm volatile("" ::: "memory");

        // prefetch chunk c+2 into the buffer just vacated
        if (c + 2 < NCHUNK) {
            #pragma unroll
            for (int t = 0; t < 6; ++t)
                GLD16(hiP + goff[t] + (uint32_t)(c + 2) * CSLAB,
                      &sm[cur + (size_t)(tid + NTHREADS * t) * 8]);
        }
        __builtin_amdgcn_sched_barrier(0);     // keep issue ahead of MFMA cluster

        __builtin_amdgcn_s_setprio(1);
        #pragma unroll
        for (int rb = 0; rb < 2; ++rb)
            #pragma unroll
            for (int cb = 0; cb < 4; ++cb) {
                acc[rb][cb] = __builtin_amdgcn_mfma_f32_16x16x32_f16(ah[rb], bh[cb], acc[rb][cb], 0, 0, 0);
                acc[rb][cb] = __builtin_amdgcn_mfma_f32_16x16x32_f16(ah[rb], bl[cb], acc[rb][cb], 0, 0, 0);
                acc[rb][cb] = __builtin_amdgcn_mfma_f32_16x16x32_f16(al[rb], bh[cb], acc[rb][cb], 0, 0, 0);
            }
        __builtin_amdgcn_s_setprio(0);
    }

    // masked score tile into LDS. C/D: col = lane&15, row = (lane>>4)*4 + reg
    {
        const int qn = lane >> 4, rn = lane & 15;
        #pragma unroll
        for (int rb = 0; rb < 2; ++rb)
            #pragma unroll
            for (int cb = 0; cb < 4; ++cb)
                #pragma unroll
                for (int reg = 0; reg < 4; ++reg) {
                    const int i_loc = 32 * wr + 16 * rb + qn * 4 + reg;
                    const int j_loc = 64 * wc + 16 * cb + rn;
                    scores[i_loc * CST + j_loc] =
                        (j0 + j_loc <= i0 + i_loc) ? acc[rb][cb][reg] : -INFINITY;
                }
    }
    __syncthreads();

    // per-window top-K: 4 threads/row (same wave), 32 candidates in registers,
    // dead-bitmask zap, 2-step shfl_xor quad merge — no barriers.
    const int rloc = tid >> 2, seg = tid & 3;
    const float* Crow = scores + rloc * CST;
    float vals[32];
    #pragma unroll
    for (int cc = 0; cc < 32; ++cc) vals[cc] = Crow[seg + 4 * cc];

    uint32_t dead = 0;
    const int irow = i0 + rloc;
    const size_t obase = ((size_t)(b * TT + irow) * NJC + jc) * KMAX;
    for (int k = 0; k < K; ++k) {
        float bv = -INFINITY; int bcc = -1;
        #pragma unroll
        for (int cc = 0; cc < 32; ++cc) {
            const bool alive = ((dead >> cc) & 1u) == 0u;
            if (alive && vals[cc] > bv) { bv = vals[cc]; bcc = cc; }
        }
        const int bcol = (bcc >= 0) ? (seg + 4 * bcc) : -1;
        float wv = bv; int wcol = bcol;
        #pragma unroll
        for (int m = 1; m < 4; m <<= 1) {
            const float ov = __shfl_xor(wv, m, 64);
            const int   oc = __shfl_xor(wcol, m, 64);
            if (ov > wv || (ov == wv && (unsigned)oc < (unsigned)wcol)) { wv = ov; wcol = oc; }
        }
        if (seg == 0) {
            pval[obase + k] = wv;
            pidx[obase + k] = (wcol >= 0) ? (j0 + wcol) : -1;
        }
        if (bcc >= 0 && wcol == bcol) dead |= (1u << bcc);
    }
}

// ---- Kernel T: rank-parallel window-merge (all 256 threads), gather, epilogue ----
// XCD-aware bijective row swizzle (T1): grid 4096 % 8 XCDs == 0, so
// row = (bid&7)*512 + bid/8 gives each XCD a contiguous 512-row span ->
// gathered h rows (heavily shared between neighboring i) stay in that
// XCD's L2 instead of being re-fetched from HBM by all 8 XCDs.
template<int K>
__global__ __launch_bounds__(NTHREADS) void merge_agg_kernel(
    const float* __restrict__ h_in,
    float* __restrict__ h_out,
    const float* __restrict__ pval,
    const int*   __restrict__ pidx,
    const float* __restrict__ gain,
    const float* __restrict__ bias,
    const float* __restrict__ log_mix_r,
    const float* __restrict__ log_momentum,
    const float* __restrict__ xres,       // non-null => fused (h-x)*scale
    const float* __restrict__ log_scale,
    _Float16* __restrict__ hiO,           // non-null => emit fp16 planes of h_out
    _Float16* __restrict__ loO)
{
    constexpr int KL = (K == 4) ? 2 : (K == 8) ? 3 : 4;
    __shared__ __align__(16) float s_cval[NTHREADS];
    __shared__ __align__(16) int   s_cidx[NTHREADS];
    __shared__ int s_sel[KMAX];

    const int bid = blockIdx.x;
    const int row = ((bid & 7) << 9) | (bid >> 3);   // XCD-contiguous (4096 = 8*512)
    const int b = row / TT, i = row % TT;
    const int tid = threadIdx.x;
    const float* hb = h_in + (size_t)b * TT * DD;

    const int count = (i + 1 < K) ? (i + 1) : K;
    const int jcn = i / CT + 1;
    const int ncand = jcn * K;          // <= 256

    // load my candidate (1 per thread)
    float mv = -INFINITY; int mj = -1;
    if (tid < ncand) {
        const int w = tid >> KL, k = tid & (K - 1);
        const size_t base = ((size_t)(b * TT + i) * NJC + w) * KMAX + k;
        const int j = pidx[base];
        if (j >= 0) { mj = j; mv = pval[base]; }
    }
    s_cval[tid] = mv;
    s_cidx[tid] = mj;

    // independent operand loads hoisted before the barrier
    const float4 hi = ((const float4*)(hb + (size_t)i * DD))[tid];
    const float4 g4 = ((const float4*)gain)[tid];
    const float4 c4 = ((const float4*)bias)[tid];
    __syncthreads();   // candidates staged

    // rank scan: uniform float4/int4 LDS reads (broadcast, conflict-free)
    if (mj >= 0) {
        const int nb = (ncand + 3) >> 2;
        int rank = 0;
        for (int q = 0; q < nb; ++q) {
            const float4 v4 = ((const float4*)s_cval)[q];
            const int4  j4 = ((const int4*)s_cidx)[q];
            rank += (v4.x > mv || (v4.x == mv && (unsigned)j4.x < (unsigned)mj));
            rank += (v4.y > mv || (v4.y == mv && (unsigned)j4.y < (unsigned)mj));
            rank += (v4.z > mv || (v4.z == mv && (unsigned)j4.z < (unsigned)mj));
            rank += (v4.w > mv || (v4.w == mv && (unsigned)j4.w < (unsigned)mj));
        }
        if (rank < count) s_sel[rank] = mj;   // ranks unique -> no race
    }
    __syncthreads();   // s_sel visible

    const float mix      = 1.0f / (1.0f + expf(-log_mix_r[0]));
    const float momentum = 1.0f / (1.0f + expf(-log_momentum[0]));
    const float inv_cnt  = 1.0f / (float)count;

    float4 msg = make_float4(0.f, 0.f, 0.f, 0.f);
    if (count == K) {   // common path: fully unrolled, all K gathers in flight
        #pragma unroll
        for (int k = 0; k < K; ++k) {
            const float4 v = ((const float4*)(hb + (size_t)s_sel[k] * DD))[tid];
            msg.x += v.x; msg.y += v.y; msg.z += v.z; msg.w += v.w;
        }
    } else {
        for (int k = 0; k < count; ++k) {
            const float4 v = ((const float4*)(hb + (size_t)s_sel[k] * DD))[tid];
            msg.x += v.x; msg.y += v.y; msg.z += v.z; msg.w += v.w;
        }
    }

    float4 o;
    {
        float m, t;
        m = msg.x * inv_cnt; t = (mix * hi.x + (1.f - mix) * m) * g4.x + c4.x;
        o.x = momentum * hi.x + (1.f - momentum) * gelu_exact(t);
        m = msg.y * inv_cnt; t = (mix * hi.y + (1.f - mix) * m) * g4.y + c4.y;
        o.y = momentum * hi.y + (1.f - momentum) * gelu_exact(t);
        m = msg.z * inv_cnt; t = (mix * hi.z + (1.f - mix) * m) * g4.z + c4.z;
        o.z = momentum * hi.z + (1.f - momentum) * gelu_exact(t);
        m = msg.w * inv_cnt; t = (mix * hi.w + (1.f - mix) * m) * g4.w + c4.w;
        o.w = momentum * hi.w + (1.f - momentum) * gelu_exact(t);
    }

    if (hiO != nullptr) {   // planes of h_next (pre-finalize value), K-blocked
        const float os[4] = {o.x, o.y, o.z, o.w};
        half4v hv, lv;
        #pragma unroll
        for (int u = 0; u < 4; ++u) {
            const _Float16 hh = (_Float16)os[u];
            hv[u] = hh;
            lv[u] = (_Float16)(os[u] - (float)hh);
        }
        const uint32_t wh  = (uint32_t)tid * 4u;     // half index within row
        const uint32_t off = ((wh >> 5) * (uint32_t)NROWS + (uint32_t)row) * 32u + (wh & 31u);
        *(half4v*)(hiO + off) = hv;
        *(half4v*)(loO + off) = lv;
    }

    if (xres != nullptr) {
        const float scale = log1pf(expf(log_scale[0])) + 0.01f;
        const float4 xv = ((const float4*)(xres + (size_t)row * DD))[tid];
        o.x = (o.x - xv.x) * scale;
        o.y = (o.y - xv.y) * scale;
        o.z = (o.z - xv.z) * scale;
        o.w = (o.w - xv.w) * scale;
    }
    ((float4*)(h_out + (size_t)row * DD))[tid] = o;
}

extern "C" void kernel_launch(void* const* d_in, const int* in_sizes, int n_in,
                              void* d_out, int out_size, void* d_ws, size_t ws_size,
                              hipStream_t stream) {
    const float* x            = (const float*)d_in[0];
    const float* gain         = (const float*)d_in[1];
    const float* bias         = (const float*)d_in[2];
    const float* log_mix      = (const float*)d_in[3];
    const float* log_momentum = (const float*)d_in[4];
    const float* log_scale    = (const float*)d_in[5];
    float* out = (float*)d_out;

    // ws: h (16.78 MB) | pval (4.19) | pidx (4.19) | hiP (8.39) | loP (8.39, contiguous)
    char* wsb = (char*)d_ws;
    float*     h_ws = (float*)wsb;
    float*     pval = (float*)(wsb + (size_t)BB * TT * DD * 4);
    int*       pidx = (int*)  (wsb + (size_t)BB * TT * DD * 4 + (size_t)BB * TT * NJC * KMAX * 4);
    _Float16*  hiP  = (_Float16*)(wsb + (size_t)BB * TT * DD * 4 + (size_t)BB * TT * NJC * KMAX * 8);
    _Float16*  loP  = hiP + (size_t)PLANE;   // must stay contiguous (score kernel offsets)

    const dim3 sgrid(NTILES, BB);
    const int nsplit = BB * TT * DD / 4 / NTHREADS;

    // round 0: x -> out (merge emits planes of h1)
    split_kernel<<<nsplit, NTHREADS, 0, stream>>>(x, hiP, loP);
    score_topk_kernel<<<sgrid, NTHREADS, 0, stream>>>(hiP, pval, pidx, 4);
    merge_agg_kernel<4><<<BB * TT, NTHREADS, 0, stream>>>(
        x, out, pval, pidx, gain + 0 * DD, bias + 0 * DD, log_mix + 0, log_momentum,
        nullptr, nullptr, hiP, loP);
    // round 1: out -> h_ws (merge emits planes of h2)
    score_topk_kernel<<<sgrid, NTHREADS, 0, stream>>>(hiP, pval, pidx, 8);
    merge_agg_kernel<8><<<BB * TT, NTHREADS, 0, stream>>>(
        out, h_ws, pval, pidx, gain + 1 * DD, bias + 1 * DD, log_mix + 1, log_momentum,
        nullptr, nullptr, hiP, loP);
    // round 2 (fused finalize): h_ws -> out
    score_topk_kernel<<<sgrid, NTHREADS, 0, stream>>>(hiP, pval, pidx, 16);
    merge_agg_kernel<16><<<BB * TT, NTHREADS, 0, stream>>>(
        h_ws, out, pval, pidx, gain + 2 * DD, bias + 2 * DD, log_mix + 2, log_momentum,
        x, log_scale, nullptr, nullptr);
}

// Round 9
// 296.323 us; speedup vs baseline: 1.0612x; 1.0612x over previous
//
#include <hip/hip_runtime.h>
#include <math.h>

#define BB 2
#define TT 2048
#define DD 1024
#define NTHREADS 256

#define RT 64               // rows per score tile
#define CT 128              // cols per score tile (= top-K window width)
#define DC 32               // d-halves per chunk = 1 MFMA K-step
#define NCHUNK (DD / DC)    // 32
#define NJC (TT / CT)       // 16 windows per row
#define KMAX 16
#define CST 132             // score-tile stride: 4 mod 32 -> 2-way (free) scans
#define NTILES 272          // causal 64x128 tiles per batch
#define NROWS (BB * TT)     // 4096 global rows
#define CSLAB ((uint32_t)(NROWS * DC))     // halves per chunk slab (256 KB)
#define PLANE ((uint32_t)(BB * TT * DD))   // halves per plane (hi->lo offset)
#define HBUF 12288          // halves per staging buffer (24 KB)

// K-blocked plane layout: half (row, d) lives at plane[(d/32)*NROWS*32 + row*32 + d%32].
// A chunk c of any 16-row band is 1 KB contiguous -> every global_load_lds is a
// full-line, sequential read.

typedef _Float16 half8  __attribute__((ext_vector_type(8)));
typedef _Float16 half4v __attribute__((ext_vector_type(4)));
typedef float    float4v __attribute__((ext_vector_type(4)));

#define GLD16(gp, lp) __builtin_amdgcn_global_load_lds(                         \
    (const __attribute__((address_space(1))) unsigned int*)(gp),                \
    (__attribute__((address_space(3))) unsigned int*)(lp), 16, 0, 0)

__device__ __forceinline__ float gelu_exact(float t) {
    return 0.5f * t * (1.0f + erff(t * 0.70710678118654752f));
}

// ---- Kernel P: split fp32 h into fp16 hi/lo planes, K-blocked layout ----
__global__ __launch_bounds__(NTHREADS) void split_kernel(
    const float* __restrict__ h,
    _Float16* __restrict__ hiP,
    _Float16* __restrict__ loP)
{
    const int idx = blockIdx.x * NTHREADS + threadIdx.x;   // float4 index
    const float4 v = ((const float4*)h)[idx];
    const float xs[4] = {v.x, v.y, v.z, v.w};
    half4v hi, lo;
    #pragma unroll
    for (int u = 0; u < 4; ++u) {
        const _Float16 hh = (_Float16)xs[u];
        hi[u] = hh;
        lo[u] = (_Float16)(xs[u] - (float)hh);
    }
    const uint32_t tot  = (uint32_t)idx * 4u;      // half index in row-major h
    const uint32_t grow = tot >> 10;               // global row (DD=1024)
    const uint32_t wh   = tot & 1023u;             // half within row
    const uint32_t off  = ((wh >> 5) * (uint32_t)NROWS + grow) * 32u + (wh & 31u);
    *(half4v*)(hiP + off) = hi;
    *(half4v*)(loP + off) = lo;
}

// ---- Kernel S: causal 64x128 score tile, DMA-staged split-fp16 MFMA,
//   K-blocked layout, SINGLE-BARRIER READ-AHEAD PIPELINE:
//   fragments for chunk c+1 are ds_read into a second register set BEFORE
//   chunk c's MFMA cluster. The one barrier per chunk proves both guards at
//   once: each wave does lgkmcnt(0) (its reads of buf[c&1] done) and vmcnt(0)
//   (its DMA(c+1) granules landed) immediately before arriving, so after the
//   barrier buf[c&1] is free for DMA(c+2) and buf[(c+1)&1] is fully valid.
//   ds_read latency retires under the MFMA cluster + loop-back (compiler
//   emits non-blocking lgkmcnt(12) before the MFMAs). 2x24KB buffers ->
//   3 blocks/CU preserved. --------------------------------------------------
// Staging buffer layout (granule = 16 B = 8 halves, fragment-lane order):
//   A-hi granules [0,256), A-lo [256,512), B-hi [512,1024), B-lo [1024,1536).
//   granule n (within region): row = 16*band + (n&15), k-oct = (n>>4)&3,
//   band = n>>6. Global addr of granule = pl*PLANE + c*CSLAB + grow*DC + oct*8.
__global__ __launch_bounds__(NTHREADS, 3) void score_topk_kernel(
    const _Float16* __restrict__ hiP,   // loP = hiP + PLANE
    float* __restrict__ pval,   // (B,T,NJC,KMAX)
    int*   __restrict__ pidx,   // (B,T,NJC,KMAX)
    int K)
{
    __shared__ __align__(16) char smem_raw[49152];  // 2x24KB staging / 64x132 f32 scores
    _Float16* sm  = (_Float16*)smem_raw;
    float* scores = (float*)smem_raw;

    // triangular decode: p -> (it, jc); it in [0,32), jc in [0, it/2]
    const int b = blockIdx.y;
    const int p = blockIdx.x;
    int g = (int)(0.5f * (sqrtf(4.0f * (float)p + 1.0f) - 1.0f));
    while ((g + 1) * (g + 2) <= p) ++g;
    while (g * (g + 1) > p) --g;
    const int qq = p - g * (g + 1);
    const int it = 2 * g + qq / (g + 1);
    const int jc = qq % (g + 1);
    const int i0 = it * RT, j0 = jc * CT;

    const int tid  = threadIdx.x;
    const int lane = tid & 63, wave = tid >> 6;
    const int wr = wave & 1, wc = wave >> 1;

    // 6 DMA slots/thread/chunk: granule gr = tid + 256*slot
    uint32_t goff[6];
    #pragma unroll
    for (int slot = 0; slot < 6; ++slot) {
        const int gr = tid + NTHREADS * slot;   // 0..1535
        int n, row; uint32_t pl;
        if (gr < 256)       { n = gr;        pl = 0; row = i0 + 16 * (n >> 6) + (n & 15); }
        else if (gr < 512)  { n = gr - 256;  pl = 1; row = i0 + 16 * (n >> 6) + (n & 15); }
        else if (gr < 1024) { n = gr - 512;  pl = 0; row = j0 + 16 * (n >> 6) + (n & 15); }
        else                { n = gr - 1024; pl = 1; row = j0 + 16 * (n >> 6) + (n & 15); }
        const int oct = (n >> 4) & 3;
        goff[slot] = pl * PLANE + (uint32_t)(b * TT + row) * DC + (uint32_t)oct * 8;
    }

    float4v acc[2][4];
    #pragma unroll
    for (int rb = 0; rb < 2; ++rb)
        #pragma unroll
        for (int cb = 0; cb < 4; ++cb)
            acc[rb][cb] = (float4v){0.f, 0.f, 0.f, 0.f};

    // fragment register double-buffer (E = even chunks, O = odd chunks)
    half8 ahE[2], alE[2], bhE[4], blE[4];
    half8 ahO[2], alO[2], bhO[4], blO[4];

#define LDFRAG(AH, AL, BH, BL, BASE) do {                                        \
        _Pragma("unroll")                                                        \
        for (int rb = 0; rb < 2; ++rb) {                                         \
            const int band = 2 * wr + rb;                                        \
            AH[rb] = *(const half8*)&sm[(BASE) +        (band * 64 + lane) * 8]; \
            AL[rb] = *(const half8*)&sm[(BASE) + 2048 + (band * 64 + lane) * 8]; \
        }                                                                        \
        _Pragma("unroll")                                                        \
        for (int cb = 0; cb < 4; ++cb) {                                         \
            const int band = 4 * wc + cb;                                        \
            BH[cb] = *(const half8*)&sm[(BASE) + 4096 + (band * 64 + lane) * 8]; \
            BL[cb] = *(const half8*)&sm[(BASE) + 8192 + (band * 64 + lane) * 8]; \
        }                                                                        \
    } while (0)

#define DOMFMA(AH, AL, BH, BL) do {                                              \
        __builtin_amdgcn_s_setprio(1);                                           \
        _Pragma("unroll")                                                        \
        for (int rb = 0; rb < 2; ++rb)                                           \
            _Pragma("unroll")                                                    \
            for (int cb = 0; cb < 4; ++cb) {                                     \
                acc[rb][cb] = __builtin_amdgcn_mfma_f32_16x16x32_f16(            \
                    AH[rb], BH[cb], acc[rb][cb], 0, 0, 0);                       \
                acc[rb][cb] = __builtin_amdgcn_mfma_f32_16x16x32_f16(            \
                    AH[rb], BL[cb], acc[rb][cb], 0, 0, 0);                       \
                acc[rb][cb] = __builtin_amdgcn_mfma_f32_16x16x32_f16(            \
                    AL[rb], BH[cb], acc[rb][cb], 0, 0, 0);                       \
            }                                                                    \
        __builtin_amdgcn_s_setprio(0);                                           \
    } while (0)

    // one pipeline iteration for chunk c:
    //   lgkm(0): my frag[c] reads (issued last iter) complete
    //   vmcnt(0): my DMA(c+1) granules landed (issued last iter)
    //   barrier:  => buf[c&1] free for all, buf[(c+1)&1] valid for all
    //   DMA(c+2) -> buf[c&1] ; ds_read frag[c+1] <- buf[(c+1)&1] ; MFMA frag[c]
#define PIPE(BCUR, BNXT, FaH, FaL, FbH, FbL, NaH, NaL, NbH, NbL, DO_DMA)         \
    do {                                                                         \
        asm volatile("s_waitcnt lgkmcnt(0)" ::: "memory");                       \
        asm volatile("s_waitcnt vmcnt(0)"  ::: "memory");                        \
        __builtin_amdgcn_s_barrier();                                            \
        __builtin_amdgcn_sched_barrier(0);                                       \
        if (DO_DMA) {                                                            \
            _Pragma("unroll")                                                    \
            for (int t = 0; t < 6; ++t)                                          \
                GLD16(hiP + goff[t] + coff,                                      \
                      &sm[(BCUR) + (size_t)(tid + NTHREADS * t) * 8]);           \
            coff += (uint32_t)CSLAB;                                             \
        }                                                                        \
        __builtin_amdgcn_sched_barrier(0);                                       \
        LDFRAG(NaH, NaL, NbH, NbL, BNXT);                                        \
        __builtin_amdgcn_sched_barrier(0);                                       \
        DOMFMA(FaH, FaL, FbH, FbL);                                              \
    } while (0)

    // prologue: DMA chunk 0 -> buf0, chunk 1 -> buf1; make buf0 valid; read frag0
    #pragma unroll
    for (int t = 0; t < 6; ++t)
        GLD16(hiP + goff[t], &sm[(size_t)(tid + NTHREADS * t) * 8]);
    #pragma unroll
    for (int t = 0; t < 6; ++t)
        GLD16(hiP + goff[t] + CSLAB, &sm[HBUF + (size_t)(tid + NTHREADS * t) * 8]);
    asm volatile("s_waitcnt vmcnt(6)" ::: "memory");
    __builtin_amdgcn_s_barrier();
    asm volatile("" ::: "memory");
    LDFRAG(ahE, alE, bhE, blE, 0);      // fragments of chunk 0

    uint32_t coff = 2u * CSLAB;         // global offset of chunk c+2 at c=0

    for (int ci = 0; ci < 15; ++ci) {   // chunks 0..29
        PIPE(0,    HBUF, ahE, alE, bhE, blE, ahO, alO, bhO, blO, 1);  // even c
        PIPE(HBUF, 0,    ahO, alO, bhO, blO, ahE, alE, bhE, blE, 1);  // odd c
    }
    // c = 30: no DMA to issue (c+2 = 32); still read frag31
    PIPE(0, HBUF, ahE, alE, bhE, blE, ahO, alO, bhO, blO, 0);
    // c = 31: final chunk, fragments already in regs
    asm volatile("s_waitcnt lgkmcnt(0)" ::: "memory");
    __builtin_amdgcn_sched_barrier(0);
    DOMFMA(ahO, alO, bhO, blO);
#undef PIPE
#undef DOMFMA
#undef LDFRAG

    __syncthreads();   // all waves past their last LDS reads before overwrite

    // masked score tile into LDS. C/D: col = lane&15, row = (lane>>4)*4 + reg
    {
        const int qn = lane >> 4, rn = lane & 15;
        #pragma unroll
        for (int rb = 0; rb < 2; ++rb)
            #pragma unroll
            for (int cb = 0; cb < 4; ++cb)
                #pragma unroll
                for (int reg = 0; reg < 4; ++reg) {
                    const int i_loc = 32 * wr + 16 * rb + qn * 4 + reg;
                    const int j_loc = 64 * wc + 16 * cb + rn;
                    scores[i_loc * CST + j_loc] =
                        (j0 + j_loc <= i0 + i_loc) ? acc[rb][cb][reg] : -INFINITY;
                }
    }
    __syncthreads();

    // per-window top-K: 4 threads/row (same wave), 32 candidates in registers,
    // dead-bitmask zap, 2-step shfl_xor quad merge — no barriers.
    const int rloc = tid >> 2, seg = tid & 3;
    const float* Crow = scores + rloc * CST;
    float vals[32];
    #pragma unroll
    for (int cc = 0; cc < 32; ++cc) vals[cc] = Crow[seg + 4 * cc];

    uint32_t dead = 0;
    const int irow = i0 + rloc;
    const size_t obase = ((size_t)(b * TT + irow) * NJC + jc) * KMAX;
    for (int k = 0; k < K; ++k) {
        float bv = -INFINITY; int bcc = -1;
        #pragma unroll
        for (int cc = 0; cc < 32; ++cc) {
            const bool alive = ((dead >> cc) & 1u) == 0u;
            if (alive && vals[cc] > bv) { bv = vals[cc]; bcc = cc; }
        }
        const int bcol = (bcc >= 0) ? (seg + 4 * bcc) : -1;
        float wv = bv; int wcol = bcol;
        #pragma unroll
        for (int m = 1; m < 4; m <<= 1) {
            const float ov = __shfl_xor(wv, m, 64);
            const int   oc = __shfl_xor(wcol, m, 64);
            if (ov > wv || (ov == wv && (unsigned)oc < (unsigned)wcol)) { wv = ov; wcol = oc; }
        }
        if (seg == 0) {
            pval[obase + k] = wv;
            pidx[obase + k] = (wcol >= 0) ? (j0 + wcol) : -1;
        }
        if (bcc >= 0 && wcol == bcol) dead |= (1u << bcc);
    }
}

// ---- Kernel T: rank-parallel window-merge (all 256 threads), gather, epilogue ----
// Selection: candidate ci (<=256) gets rank = #{c' : v' > v || (v'==v && j'<j)}
// via a broadcast LDS scan; rank < count wins slot s_sel[rank]. Identical set
// and order as the old iterative-max merge (same tie-break), but fully parallel.
template<int K>
__global__ __launch_bounds__(NTHREADS) void merge_agg_kernel(
    const float* __restrict__ h_in,
    float* __restrict__ h_out,
    const float* __restrict__ pval,
    const int*   __restrict__ pidx,
    const float* __restrict__ gain,
    const float* __restrict__ bias,
    const float* __restrict__ log_mix_r,
    const float* __restrict__ log_momentum,
    const float* __restrict__ xres,       // non-null => fused (h-x)*scale
    const float* __restrict__ log_scale,
    _Float16* __restrict__ hiO,           // non-null => emit fp16 planes of h_out
    _Float16* __restrict__ loO)
{
    constexpr int KL = (K == 4) ? 2 : (K == 8) ? 3 : 4;
    __shared__ __align__(16) float s_cval[NTHREADS];
    __shared__ __align__(16) int   s_cidx[NTHREADS];
    __shared__ int s_sel[KMAX];

    const int row = blockIdx.x, b = row / TT, i = row % TT;
    const int tid = threadIdx.x;
    const float* hb = h_in + (size_t)b * TT * DD;

    const int count = (i + 1 < K) ? (i + 1) : K;
    const int jcn = i / CT + 1;
    const int ncand = jcn * K;          // <= 256

    // load my candidate (1 per thread)
    float mv = -INFINITY; int mj = -1;
    if (tid < ncand) {
        const int w = tid >> KL, k = tid & (K - 1);
        const size_t base = ((size_t)(b * TT + i) * NJC + w) * KMAX + k;
        const int j = pidx[base];
        if (j >= 0) { mj = j; mv = pval[base]; }
    }
    s_cval[tid] = mv;
    s_cidx[tid] = mj;

    // independent operand loads hoisted before the barrier
    const float4 hi = ((const float4*)(hb + (size_t)i * DD))[tid];
    const float4 g4 = ((const float4*)gain)[tid];
    const float4 c4 = ((const float4*)bias)[tid];
    __syncthreads();   // candidates staged

    // rank scan: uniform float4/int4 LDS reads (broadcast, conflict-free)
    if (mj >= 0) {
        const int nb = (ncand + 3) >> 2;
        int rank = 0;
        for (int q = 0; q < nb; ++q) {
            const float4 v4 = ((const float4*)s_cval)[q];
            const int4  j4 = ((const int4*)s_cidx)[q];
            rank += (v4.x > mv || (v4.x == mv && (unsigned)j4.x < (unsigned)mj));
            rank += (v4.y > mv || (v4.y == mv && (unsigned)j4.y < (unsigned)mj));
            rank += (v4.z > mv || (v4.z == mv && (unsigned)j4.z < (unsigned)mj));
            rank += (v4.w > mv || (v4.w == mv && (unsigned)j4.w < (unsigned)mj));
        }
        if (rank < count) s_sel[rank] = mj;   // ranks unique -> no race
    }
    __syncthreads();   // s_sel visible

    const float mix      = 1.0f / (1.0f + expf(-log_mix_r[0]));
    const float momentum = 1.0f / (1.0f + expf(-log_momentum[0]));
    const float inv_cnt  = 1.0f / (float)count;

    float4 msg = make_float4(0.f, 0.f, 0.f, 0.f);
    if (count == K) {   // common path: fully unrolled, all K gathers in flight
        #pragma unroll
        for (int k = 0; k < K; ++k) {
            const float4 v = ((const float4*)(hb + (size_t)s_sel[k] * DD))[tid];
            msg.x += v.x; msg.y += v.y; msg.z += v.z; msg.w += v.w;
        }
    } else {
        for (int k = 0; k < count; ++k) {
            const float4 v = ((const float4*)(hb + (size_t)s_sel[k] * DD))[tid];
            msg.x += v.x; msg.y += v.y; msg.z += v.z; msg.w += v.w;
        }
    }

    float4 o;
    {
        float m, t;
        m = msg.x * inv_cnt; t = (mix * hi.x + (1.f - mix) * m) * g4.x + c4.x;
        o.x = momentum * hi.x + (1.f - momentum) * gelu_exact(t);
        m = msg.y * inv_cnt; t = (mix * hi.y + (1.f - mix) * m) * g4.y + c4.y;
        o.y = momentum * hi.y + (1.f - momentum) * gelu_exact(t);
        m = msg.z * inv_cnt; t = (mix * hi.z + (1.f - mix) * m) * g4.z + c4.z;
        o.z = momentum * hi.z + (1.f - momentum) * gelu_exact(t);
        m = msg.w * inv_cnt; t = (mix * hi.w + (1.f - mix) * m) * g4.w + c4.w;
        o.w = momentum * hi.w + (1.f - momentum) * gelu_exact(t);
    }

    if (hiO != nullptr) {   // planes of h_next (pre-finalize value), K-blocked
        const float os[4] = {o.x, o.y, o.z, o.w};
        half4v hv, lv;
        #pragma unroll
        for (int u = 0; u < 4; ++u) {
            const _Float16 hh = (_Float16)os[u];
            hv[u] = hh;
            lv[u] = (_Float16)(os[u] - (float)hh);
        }
        const uint32_t wh  = (uint32_t)tid * 4u;     // half index within row
        const uint32_t off = ((wh >> 5) * (uint32_t)NROWS + (uint32_t)row) * 32u + (wh & 31u);
        *(half4v*)(hiO + off) = hv;
        *(half4v*)(loO + off) = lv;
    }

    if (xres != nullptr) {
        const float scale = log1pf(expf(log_scale[0])) + 0.01f;
        const float4 xv = ((const float4*)(xres + (size_t)row * DD))[tid];
        o.x = (o.x - xv.x) * scale;
        o.y = (o.y - xv.y) * scale;
        o.z = (o.z - xv.z) * scale;
        o.w = (o.w - xv.w) * scale;
    }
    ((float4*)(h_out + (size_t)row * DD))[tid] = o;
}

extern "C" void kernel_launch(void* const* d_in, const int* in_sizes, int n_in,
                              void* d_out, int out_size, void* d_ws, size_t ws_size,
                              hipStream_t stream) {
    const float* x            = (const float*)d_in[0];
    const float* gain         = (const float*)d_in[1];
    const float* bias         = (const float*)d_in[2];
    const float* log_mix      = (const float*)d_in[3];
    const float* log_momentum = (const float*)d_in[4];
    const float* log_scale    = (const float*)d_in[5];
    float* out = (float*)d_out;

    // ws: h (16.78 MB) | pval (4.19) | pidx (4.19) | hiP (8.39) | loP (8.39, contiguous)
    char* wsb = (char*)d_ws;
    float*     h_ws = (float*)wsb;
    float*     pval = (float*)(wsb + (size_t)BB * TT * DD * 4);
    int*       pidx = (int*)  (wsb + (size_t)BB * TT * DD * 4 + (size_t)BB * TT * NJC * KMAX * 4);
    _Float16*  hiP  = (_Float16*)(wsb + (size_t)BB * TT * DD * 4 + (size_t)BB * TT * NJC * KMAX * 8);
    _Float16*  loP  = hiP + (size_t)PLANE;   // must stay contiguous (score kernel offsets)

    const dim3 sgrid(NTILES, BB);
    const int nsplit = BB * TT * DD / 4 / NTHREADS;

    // round 0: x -> out (merge emits planes of h1)
    split_kernel<<<nsplit, NTHREADS, 0, stream>>>(x, hiP, loP);
    score_topk_kernel<<<sgrid, NTHREADS, 0, stream>>>(hiP, pval, pidx, 4);
    merge_agg_kernel<4><<<BB * TT, NTHREADS, 0, stream>>>(
        x, out, pval, pidx, gain + 0 * DD, bias + 0 * DD, log_mix + 0, log_momentum,
        nullptr, nullptr, hiP, loP);
    // round 1: out -> h_ws (merge emits planes of h2)
    score_topk_kernel<<<sgrid, NTHREADS, 0, stream>>>(hiP, pval, pidx, 8);
    merge_agg_kernel<8><<<BB * TT, NTHREADS, 0, stream>>>(
        out, h_ws, pval, pidx, gain + 1 * DD, bias + 1 * DD, log_mix + 1, log_momentum,
        nullptr, nullptr, hiP, loP);
    // round 2 (fused finalize): h_ws -> out
    score_topk_kernel<<<sgrid, NTHREADS, 0, stream>>>(hiP, pval, pidx, 16);
    merge_agg_kernel<16><<<BB * TT, NTHREADS, 0, stream>>>(
        h_ws, out, pval, pidx, gain + 2 * DD, bias + 2 * DD, log_mix + 2, log_momentum,
        x, log_scale, nullptr, nullptr);
}